// Round 1
// baseline (813.152 us; speedup 1.0000x reference)
//
#include <hip/hip_runtime.h>
#include <cstddef>

// Problem constants (B,H,N) = (256,128,2048), K2 = 2H = 256 contraction after
// splitting off the decoder term.
#define Bn   256
#define Hd   128
#define Nd   2048
#define K3   384   // 3H, W row stride

// ---------------------------------------------------------------------------
// prep 1: Wt[k][h] = W[h][k] for k in [0,256)  (static+dynamic columns only)
// 32768 elements, tiny.
__global__ void prep_wt(const float* __restrict__ W, float* __restrict__ Wt) {
    int idx = blockIdx.x * blockDim.x + threadIdx.x;   // 0..32767
    int k = idx >> 7;          // 0..255
    int h = idx & 127;
    Wt[idx] = W[h * K3 + k];
}

// prep 2: c[b][h] = sum_k W[h][256+k] * dec[b][k]   (decoder contribution)
__global__ void prep_c(const float* __restrict__ W, const float* __restrict__ dec,
                       float* __restrict__ cb) {
    __shared__ float dl[Hd];
    int b = blockIdx.x;
    int h = threadIdx.x;       // 128 threads
    dl[h] = dec[b * Hd + h];
    __syncthreads();
    float acc = 0.f;
    #pragma unroll 8
    for (int k = 0; k < Hd; ++k)
        acc = fmaf(W[h * K3 + 256 + k], dl[k], acc);
    cb[b * Hd + h] = acc;
}

// ---------------------------------------------------------------------------
// Main: per block (b, 64-n tile). 4 waves; wave w owns h in [32w, 32w+32).
// t[h][n] = c[b][h] + sum_k Wt[k][h] * x[k][n];  score = sum_h v[h]*tanh(t).
// Raw scores written to out; softmax'd in place by softmax_k.
__global__ __launch_bounds__(256, 4)
void score_kernel(const float* __restrict__ sh, const float* __restrict__ dh,
                  const float* __restrict__ Wt, const float* __restrict__ cb,
                  const float* __restrict__ v, float* __restrict__ out) {
    // 64 n-rows x 128 k, stride 132 (pad +4: 16B-aligned float4, bank-spread)
    __shared__ __align__(16) float xl[64 * 132];
    __shared__ float red[256];

    const int tid = threadIdx.x;
    const int nl  = tid & 63;                                  // n within tile
    const int wv  = __builtin_amdgcn_readfirstlane(tid >> 6);  // wave id, SGPR
    const int h0  = wv * 32;
    const int b   = blockIdx.y;
    const int n0  = blockIdx.x * 64;

    float acc[32];
    const float* cptr = cb + b * Hd + h0;   // uniform -> scalar loads
    #pragma unroll
    for (int j = 0; j < 32; ++j) acc[j] = cptr[j];

    for (int half = 0; half < 2; ++half) {
        const float* src = (half ? dh : sh) + (size_t)b * (Hd * Nd) + n0;
        __syncthreads();   // protect xl reads of previous half
        const int kbase = tid >> 6;
        #pragma unroll 8
        for (int r = 0; r < 32; ++r) {
            int k = (r << 2) + kbase;                  // wave-uniform k
            xl[nl * 132 + k] = src[(size_t)k * Nd + nl];  // coalesced in n
        }
        __syncthreads();
        const float* wt = Wt + (half * 128) * Hd + h0; // uniform base
        for (int kc = 0; kc < 32; ++kc) {
            float4 x4 = *reinterpret_cast<const float4*>(&xl[nl * 132 + (kc << 2)]);
            const float* w0 = wt + (kc << 2) * Hd;
            #pragma unroll
            for (int j = 0; j < 32; ++j) {
                acc[j] = fmaf(w0[j],          x4.x, acc[j]);
                acc[j] = fmaf(w0[Hd + j],     x4.y, acc[j]);
                acc[j] = fmaf(w0[2 * Hd + j], x4.z, acc[j]);
                acc[j] = fmaf(w0[3 * Hd + j], x4.w, acc[j]);
            }
        }
    }

    // partial score for this wave's 32 h values
    const float* vp = v + h0;   // uniform -> scalar
    float part = 0.f;
    #pragma unroll
    for (int j = 0; j < 32; ++j) {
        // tanh(x) = 1 - 2/(exp(2x)+1); saturates correctly for |x| large
        float t = 1.0f - __fdividef(2.0f, __expf(2.0f * acc[j]) + 1.0f);
        part = fmaf(vp[j], t, part);
    }
    red[wv * 64 + nl] = part;
    __syncthreads();
    if (tid < 64) {
        float sc = red[tid] + red[64 + tid] + red[128 + tid] + red[192 + tid];
        out[(size_t)b * Nd + n0 + tid] = sc;
    }
}

// ---------------------------------------------------------------------------
// softmax over n=2048 per b, in place on out. 256 threads, 8 n each.
__global__ void softmax_k(float* __restrict__ out) {
    int b = blockIdx.x;
    float* row = out + (size_t)b * Nd;
    int tid = threadIdx.x;

    float loc[8];
    float mx = -3.4e38f;
    #pragma unroll
    for (int i = 0; i < 8; ++i) {
        loc[i] = row[tid + (i << 8)];
        mx = fmaxf(mx, loc[i]);
    }
    #pragma unroll
    for (int off = 32; off > 0; off >>= 1) mx = fmaxf(mx, __shfl_xor(mx, off));
    __shared__ float s4[4];
    if ((tid & 63) == 0) s4[tid >> 6] = mx;
    __syncthreads();
    mx = fmaxf(fmaxf(s4[0], s4[1]), fmaxf(s4[2], s4[3]));

    float sum = 0.f;
    #pragma unroll
    for (int i = 0; i < 8; ++i) {
        loc[i] = __expf(loc[i] - mx);
        sum += loc[i];
    }
    #pragma unroll
    for (int off = 32; off > 0; off >>= 1) sum += __shfl_xor(sum, off);
    __shared__ float s4b[4];
    if ((tid & 63) == 0) s4b[tid >> 6] = sum;
    __syncthreads();
    sum = s4b[0] + s4b[1] + s4b[2] + s4b[3];

    float inv = 1.0f / sum;
    #pragma unroll
    for (int i = 0; i < 8; ++i) row[tid + (i << 8)] = loc[i] * inv;
}

// ---------------------------------------------------------------------------
extern "C" void kernel_launch(void* const* d_in, const int* in_sizes, int n_in,
                              void* d_out, int out_size, void* d_ws, size_t ws_size,
                              hipStream_t stream) {
    const float* sh  = (const float*)d_in[0];   // static_hidden [B,H,N]
    const float* dh  = (const float*)d_in[1];   // dynamic_hidden [B,H,N]
    const float* dec = (const float*)d_in[2];   // decoder_hidden [B,H]
    const float* v   = (const float*)d_in[3];   // [H]
    const float* W   = (const float*)d_in[4];   // [H, 3H]
    float* out = (float*)d_out;                 // [B,1,N] raw scores -> softmax

    float* Wt = (float*)d_ws;        // 32768 floats: Wt[k][h], k<256
    float* cb = Wt + 32768;          // 32768 floats: c[b][h]
    // ws usage: 256 KiB total

    hipLaunchKernelGGL(prep_wt, dim3(128), dim3(256), 0, stream, W, Wt);
    hipLaunchKernelGGL(prep_c,  dim3(Bn),  dim3(Hd),  0, stream, W, dec, cb);
    hipLaunchKernelGGL(score_kernel, dim3(Nd / 64, Bn), dim3(256), 0, stream,
                       sh, dh, Wt, cb, v, out);
    hipLaunchKernelGGL(softmax_k, dim3(Bn), dim3(256), 0, stream, out);
}

// Round 2
// 519.334 us; speedup vs baseline: 1.5658x; 1.5658x over previous
//
#include <hip/hip_runtime.h>
#include <cstddef>

#define Bn 256
#define Hd 128
#define Nd 2048
#define K3 384     // W row stride (3H)
#define K2 256     // contraction length (static+dynamic)

typedef _Float16 half8 __attribute__((ext_vector_type(8)));
typedef float    float4v __attribute__((ext_vector_type(4)));

__device__ __forceinline__ float fast_tanh(float x) {
    // tanh(x) = 1 - 2/(exp(2x)+1); saturates correctly at +/-inf
    return 1.0f - __fdividef(2.0f, __expf(2.0f * x) + 1.0f);
}

// ---------------------------------------------------------------------------
// prep 1: Wf[h][k] = fp16(W[h][k]) for k<256  (static+dynamic columns)
__global__ void prep_w16(const float* __restrict__ W, _Float16* __restrict__ Wf) {
    int idx = blockIdx.x * 256 + threadIdx.x;   // 0..32767
    int h = idx >> 8, k = idx & 255;
    Wf[idx] = (_Float16)W[h * K3 + k];
}

// prep 2: c[b][h] = sum_k W[h][256+k] * dec[b][k]  (decoder term, fp32 exact)
__global__ void prep_c(const float* __restrict__ W, const float* __restrict__ dec,
                       float* __restrict__ cb) {
    __shared__ float dl[Hd];
    int b = blockIdx.x;
    int h = threadIdx.x;       // 128 threads
    dl[h] = dec[b * Hd + h];
    __syncthreads();
    float acc = 0.f;
    #pragma unroll 8
    for (int k = 0; k < Hd; ++k)
        acc = fmaf(W[h * K3 + 256 + k], dl[k], acc);
    cb[b * Hd + h] = acc;
}

// ---------------------------------------------------------------------------
// Main: block = (b, 128-n tile), 256 threads = 4 waves.
// Wave w owns h in [32w, 32w+32) as 2 MFMA M-tiles; all waves share the
// 128-n range (8 N-tiles). t = c + W*x via mfma_f32_16x16x32_f16, K=256.
// W A-fragments in registers (global fp16, L2-hot). x staged to LDS fp16
// [n][k] with 16B-chunk XOR swizzle: phys_chunk = (k>>3) ^ ((n>>1)&7).
__global__ __launch_bounds__(256, 2)
void score_kernel(const float* __restrict__ shp, const float* __restrict__ dhp,
                  const _Float16* __restrict__ Wf, const float* __restrict__ cbp,
                  const float* __restrict__ v, float* __restrict__ out) {
    __shared__ __align__(16) _Float16 xl[128 * 256];   // 64 KB, swizzled
    __shared__ float red[4 * 128];

    const int tid  = threadIdx.x;
    const int w    = __builtin_amdgcn_readfirstlane(tid >> 6);  // wave id (SGPR)
    const int lane = tid & 63;
    const int qd   = lane >> 4;       // quad 0..3
    const int ln   = lane & 15;
    const int b    = blockIdx.y;
    const int n0   = blockIdx.x * 128;
    const int h0   = w * 32;

    // ---- A fragments (W) -> registers. A[m=lane&15][k=quad*8+j].
    half8 Af[2][8];
    #pragma unroll
    for (int Mt = 0; Mt < 2; ++Mt) {
        const _Float16* wp = Wf + ((h0 + Mt * 16 + ln) << 8) + qd * 8;
        #pragma unroll
        for (int kt = 0; kt < 8; ++kt)
            Af[Mt][kt] = *reinterpret_cast<const half8*>(wp + kt * 32);
    }

    // ---- acc init with decoder term: D row = quad*4 + reg
    float4v acc[2][8];
    #pragma unroll
    for (int Mt = 0; Mt < 2; ++Mt) {
        float4v c4 = *reinterpret_cast<const float4v*>(cbp + b * Hd + h0 + Mt * 16 + qd * 4);
        #pragma unroll
        for (int Nt = 0; Nt < 8; ++Nt) acc[Mt][Nt] = c4;
    }

    // ---- stage x: global [k][n] fp32 -> LDS [n][k] fp16, swizzled.
    // Each wave covers all 128 n (2 per lane) and a 64-k band.
    {
        const int n1  = 2 * lane;        // even row
        const int swz = lane & 7;        // ((n1>>1)&7) == ((n1+1)>>1)&7
        #pragma unroll
        for (int hf = 0; hf < 2; ++hf) {
            const float* src = (hf ? dhp : shp) + (size_t)b * (Hd * (size_t)Nd) + n0 + n1;
            #pragma unroll
            for (int i = 0; i < 4; ++i) {
                const int kl = i * 32 + w * 8;          // wave-uniform, 0..120
                float2 xv[8];
                #pragma unroll
                for (int j = 0; j < 8; ++j)
                    xv[j] = *reinterpret_cast<const float2*>(src + (size_t)(kl + j) * Nd);
                half8 e0, e1;
                #pragma unroll
                for (int j = 0; j < 8; ++j) {
                    e0[j] = (_Float16)xv[j].x;
                    e1[j] = (_Float16)xv[j].y;
                }
                const int ck = (hf * 128 + kl) >> 3;    // logical 16B chunk 0..31
                const int p  = ck ^ swz;
                *reinterpret_cast<half8*>(&xl[n1 * 256 + p * 8])       = e0;
                *reinterpret_cast<half8*>(&xl[(n1 + 1) * 256 + p * 8]) = e1;
            }
        }
    }
    __syncthreads();

    // ---- MFMA main loop. B[k=quad*8+j][n=lane&15].
    const int swr = (ln >> 1) & 7;
    #pragma unroll
    for (int kt = 0; kt < 8; ++kt) {
        half8 Bf[8];
        const int ckb = kt * 4 + qd;
        #pragma unroll
        for (int Nt = 0; Nt < 8; ++Nt) {
            const int row = Nt * 16 + ln;
            Bf[Nt] = *reinterpret_cast<const half8*>(&xl[row * 256 + ((ckb ^ swr) << 3)]);
        }
        #pragma unroll
        for (int Nt = 0; Nt < 8; ++Nt) {
            acc[0][Nt] = __builtin_amdgcn_mfma_f32_16x16x32_f16(Af[0][kt], Bf[Nt], acc[0][Nt], 0, 0, 0);
            acc[1][Nt] = __builtin_amdgcn_mfma_f32_16x16x32_f16(Af[1][kt], Bf[Nt], acc[1][Nt], 0, 0, 0);
        }
    }

    // ---- epilogue: score[n] = sum_m v[m] * tanh(t[m][n])
    float4v v0 = *reinterpret_cast<const float4v*>(v + h0 + qd * 4);
    float4v v1 = *reinterpret_cast<const float4v*>(v + h0 + 16 + qd * 4);
    #pragma unroll
    for (int Nt = 0; Nt < 8; ++Nt) {
        float part = 0.f;
        #pragma unroll
        for (int r = 0; r < 4; ++r) {
            part = fmaf(v0[r], fast_tanh(acc[0][Nt][r]), part);
            part = fmaf(v1[r], fast_tanh(acc[1][Nt][r]), part);
        }
        part += __shfl_xor(part, 16);   // sum quads (same n)
        part += __shfl_xor(part, 32);
        if (qd == 0) red[w * 128 + Nt * 16 + ln] = part;
    }
    __syncthreads();
    if (tid < 128) {
        float s = red[tid] + red[128 + tid] + red[256 + tid] + red[384 + tid];
        out[(size_t)b * Nd + n0 + tid] = s;
    }
}

// ---------------------------------------------------------------------------
// softmax over n=2048 per b, in place. (validated round 1)
__global__ void softmax_k(float* __restrict__ out) {
    int b = blockIdx.x;
    float* row = out + (size_t)b * Nd;
    int tid = threadIdx.x;

    float loc[8];
    float mx = -3.4e38f;
    #pragma unroll
    for (int i = 0; i < 8; ++i) {
        loc[i] = row[tid + (i << 8)];
        mx = fmaxf(mx, loc[i]);
    }
    #pragma unroll
    for (int off = 32; off > 0; off >>= 1) mx = fmaxf(mx, __shfl_xor(mx, off));
    __shared__ float s4[4];
    if ((tid & 63) == 0) s4[tid >> 6] = mx;
    __syncthreads();
    mx = fmaxf(fmaxf(s4[0], s4[1]), fmaxf(s4[2], s4[3]));

    float sum = 0.f;
    #pragma unroll
    for (int i = 0; i < 8; ++i) {
        loc[i] = __expf(loc[i] - mx);
        sum += loc[i];
    }
    #pragma unroll
    for (int off = 32; off > 0; off >>= 1) sum += __shfl_xor(sum, off);
    __shared__ float s4b[4];
    if ((tid & 63) == 0) s4b[tid >> 6] = sum;
    __syncthreads();
    sum = s4b[0] + s4b[1] + s4b[2] + s4b[3];

    float inv = 1.0f / sum;
    #pragma unroll
    for (int i = 0; i < 8; ++i) row[tid + (i << 8)] = loc[i] * inv;
}

// ---------------------------------------------------------------------------
extern "C" void kernel_launch(void* const* d_in, const int* in_sizes, int n_in,
                              void* d_out, int out_size, void* d_ws, size_t ws_size,
                              hipStream_t stream) {
    const float* shp = (const float*)d_in[0];   // static_hidden [B,H,N]
    const float* dhp = (const float*)d_in[1];   // dynamic_hidden [B,H,N]
    const float* dec = (const float*)d_in[2];   // decoder_hidden [B,H]
    const float* v   = (const float*)d_in[3];   // [H]
    const float* W   = (const float*)d_in[4];   // [H, 3H]
    float* out = (float*)d_out;                 // [B,1,N]

    _Float16* Wf = (_Float16*)d_ws;             // 32768 halves = 64 KB
    float* cbp = (float*)((char*)d_ws + 65536); // 32768 floats = 128 KB

    hipLaunchKernelGGL(prep_w16, dim3(128), dim3(256), 0, stream, W, Wf);
    hipLaunchKernelGGL(prep_c,   dim3(Bn),  dim3(Hd),  0, stream, W, dec, cbp);
    hipLaunchKernelGGL(score_kernel, dim3(Nd / 128, Bn), dim3(256), 0, stream,
                       shp, dhp, Wf, cbp, v, out);
    hipLaunchKernelGGL(softmax_k, dim3(Bn), dim3(256), 0, stream, out);
}